// Round 3
// baseline (294.396 us; speedup 1.0000x reference)
//
#include <hip/hip_runtime.h>

#define D_ 300
#define C_ 10
#define I_ 6
#define NPOS 16384
#define PPB 4                 // one wave per position, 4 waves per block
#define NBLK (NPOS / PPB)
#define NDOT 70               // 10 ctx dots + 60 ctx-info dots
#define RED_LD 71             // LDS row stride (prime-ish: banks (7g+d)%32 distinct)

__device__ __forceinline__ float neg_log_sigmoid(float x) {
    // -log_sigmoid(x) = log(1 + exp(-x)); x in [-10,10], fp32-safe
    return __logf(1.0f + __expf(-x));
}

// One wave per position; rows in registers (lane l holds k = l + 64j).
// No __syncthreads in the hot path: each wave uses a private LDS region and
// per-wave DS ordering guarantees RAW correctness.
__global__ __launch_bounds__(256, 8) void hg2vec_pos_kernel(
    const int* __restrict__ pos_u, const int* __restrict__ pos_v,
    const int* __restrict__ info_v,
    const float* __restrict__ W_in, const float* __restrict__ W_out,
    const float* __restrict__ context_mask, const float* __restrict__ sig_mask,
    const float* __restrict__ score_mask, float* __restrict__ partial)
{
    const int wave = threadIdx.x >> 6;
    const int lane = threadIdx.x & 63;
    const int p = blockIdx.x * PPB + wave;

    // [wave][group g=lane>>3][dot] — 4*8*71*4 = 9088 B total
    __shared__ float s_red[PPB][8][RED_LD];

    // Wave-uniform indices -> SGPR bases; all row loads share one lane offset
    const int su = __builtin_amdgcn_readfirstlane(pos_u[p]);
    int scv[C_], siv[I_];
#pragma unroll
    for (int c = 0; c < C_; ++c) scv[c] = __builtin_amdgcn_readfirstlane(pos_v[p * C_ + c]);
#pragma unroll
    for (int i = 0; i < I_; ++i) siv[i] = __builtin_amdgcn_readfirstlane(info_v[p * I_ + i]);

    // Tail: j=4 covers k = lane+256, valid for lane < 44; zero via okf
    const int k4 = lane + 256;
    const float okf = (k4 < D_) ? 1.0f : 0.0f;
    const int k4c = (k4 < D_) ? k4 : lane;

    const float* ur = W_out + (size_t)su * D_;
    const float u0 = ur[lane], u1 = ur[lane + 64], u2 = ur[lane + 128],
                u3 = ur[lane + 192], u4 = ur[k4c] * okf;

    float ii0[I_], ii1[I_], ii2[I_], ii3[I_], ii4[I_];
#pragma unroll
    for (int i = 0; i < I_; ++i) {
        const float* r = W_in + (size_t)siv[i] * D_;
        ii0[i] = r[lane];       ii1[i] = r[lane + 64];
        ii2[i] = r[lane + 128]; ii3[i] = r[lane + 192];
        ii4[i] = r[k4c] * okf;
    }

    const int g = lane >> 3;
    const bool writer = (lane & 7) == 0;

#pragma unroll
    for (int c = 0; c < C_; ++c) {
        const float* cir = W_in  + (size_t)scv[c] * D_;
        const float* cor = W_out + (size_t)scv[c] * D_;
        const float a0 = cir[lane], a1 = cir[lane + 64], a2 = cir[lane + 128],
                    a3 = cir[lane + 192], a4 = cir[k4c];   // a4 garbage * u4==0
        const float b0 = cor[lane], b1 = cor[lane + 64], b2 = cor[lane + 128],
                    b3 = cor[lane + 192], b4 = cor[k4c];   // b4 garbage * ii4==0

        float part[7];
        part[0] = u0 * a0 + u1 * a1 + u2 * a2 + u3 * a3 + u4 * a4;
#pragma unroll
        for (int i = 0; i < I_; ++i)
            part[1 + i] = b0 * ii0[i] + b1 * ii1[i] + b2 * ii2[i] + b3 * ii3[i] + b4 * ii4[i];

        // 3-step xor butterfly: 64 lane-partials -> 8 group sums (lanes 8g)
#pragma unroll
        for (int t = 0; t < 7; ++t) {
            float v = part[t];
            v += __shfl_xor(v, 1, 64);
            v += __shfl_xor(v, 2, 64);
            v += __shfl_xor(v, 4, 64);
            if (writer) s_red[wave][g][c * 7 + t] = v;
        }
    }

    // Read phase (wave-private region; per-wave DS ordering, no barrier).
    float acc = 0.0f;
#pragma unroll
    for (int pass = 0; pass < 2; ++pass) {
        const int d = pass * 64 + lane;
        if (d < NDOT) {
            float s = s_red[wave][0][d] + s_red[wave][1][d] + s_red[wave][2][d]
                    + s_red[wave][3][d] + s_red[wave][4][d] + s_red[wave][5][d]
                    + s_red[wave][6][d] + s_red[wave][7][d];
            const int c = d / 7;
            const int t = d - c * 7;
            if (t == 0) {
                float x = s * context_mask[c];            // mask commutes with dot
                x = fminf(fmaxf(x, -10.0f), 10.0f);
                acc += neg_log_sigmoid(x);
            } else {
                const int i = t - 1;
                float x = fminf(fmaxf(s, -10.0f), 10.0f) * sig_mask[i];
                acc += neg_log_sigmoid(x) * score_mask[i];
            }
        }
    }

#pragma unroll
    for (int off = 32; off; off >>= 1) acc += __shfl_xor(acc, off, 64);
    if (lane == 0) partial[p] = acc;
}

// Single block: 16384 floats = 4096 float4; 256 threads x 16 float4 each.
__global__ __launch_bounds__(256) void hg2vec_reduce_kernel(
    const float* __restrict__ partial, float* __restrict__ out)
{
    float a = 0.0f;
    const float4* p4 = (const float4*)partial;
    for (int i = threadIdx.x; i < NPOS / 4; i += 256) {
        float4 v = p4[i];
        a += (v.x + v.y) + (v.z + v.w);
    }
#pragma unroll
    for (int off = 32; off; off >>= 1) a += __shfl_xor(a, off, 64);
    __shared__ float s[4];
    if ((threadIdx.x & 63) == 0) s[threadIdx.x >> 6] = a;
    __syncthreads();
    if (threadIdx.x == 0) out[0] = (s[0] + s[1]) + (s[2] + s[3]);
}

extern "C" void kernel_launch(void* const* d_in, const int* in_sizes, int n_in,
                              void* d_out, int out_size, void* d_ws, size_t ws_size,
                              hipStream_t stream) {
    const int* pos_u = (const int*)d_in[0];
    const int* pos_v = (const int*)d_in[1];
    const int* info_v = (const int*)d_in[2];
    const float* W_in = (const float*)d_in[3];
    const float* W_out = (const float*)d_in[4];
    const float* context_mask = (const float*)d_in[5];
    const float* sig_mask = (const float*)d_in[6];
    const float* score_mask = (const float*)d_in[7];
    float* out = (float*)d_out;
    float* partial = (float*)d_ws;   // NPOS floats = 64 KB scratch

    hg2vec_pos_kernel<<<NBLK, 256, 0, stream>>>(
        pos_u, pos_v, info_v, W_in, W_out,
        context_mask, sig_mask, score_mask, partial);
    hg2vec_reduce_kernel<<<1, 256, 0, stream>>>(partial, out);
}